// Round 8
// baseline (623.870 us; speedup 1.0000x reference)
//
#include <hip/hip_runtime.h>
#include <hip/hip_bf16.h>

#define BATCH 8192
#define NUM_LABELS 8190
#define CURW 2944   // padded cur width (K for level 5)
#define YW   8192   // ybuf row stride

typedef __attribute__((ext_vector_type(4))) float f32x4;
typedef __attribute__((ext_vector_type(8))) short bf16x8;

#define VMCNT(n) asm volatile("s_waitcnt vmcnt(" #n ")" ::: "memory")
#define BAR() do { asm volatile("" ::: "memory"); __builtin_amdgcn_s_barrier(); asm volatile("" ::: "memory"); } while (0)
#define WAITK(n) do { asm volatile("s_waitcnt lgkmcnt(" #n ")" ::: "memory"); __builtin_amdgcn_sched_barrier(0); } while (0)

// ---------- helpers ----------
__device__ __forceinline__ unsigned short f2bf(float f) {
  unsigned u = __builtin_bit_cast(unsigned, f);
  unsigned r = u + 0x7fffu + ((u >> 16) & 1u);   // RNE; inputs are finite
  return (unsigned short)(r >> 16);
}
__device__ __forceinline__ float bf2f(unsigned short b) {
  return __builtin_bit_cast(float, (unsigned)b << 16);
}
__device__ __forceinline__ void gload_lds16(const void* g, void* l) {
  __builtin_amdgcn_global_load_lds(
      (const __attribute__((address_space(1))) void*)g,
      (__attribute__((address_space(3))) void*)l,
      16, 0, 0);
}

// ---------- fused x-convert + pad-zeroing ----------
__global__ void k_prep_x(const float* __restrict__ x,
                         unsigned short* __restrict__ xraw,
                         unsigned short* __restrict__ cur) {
  const int TX = BATCH * 768 / 4;
  int i = blockIdx.x * 256 + threadIdx.x;
  if (i < TX) {
    float4 v = ((const float4*)x)[i];
    int e = i * 4;
    int row = e / 768;
    int col = e - row * 768;
    ushort4 a, c;
    a.x = f2bf(v.x); a.y = f2bf(v.y); a.z = f2bf(v.z); a.w = f2bf(v.w);
    c.x = f2bf(fmaxf(v.x, 0.f)); c.y = f2bf(fmaxf(v.y, 0.f));
    c.z = f2bf(fmaxf(v.z, 0.f)); c.w = f2bf(fmaxf(v.w, 0.f));
    *(ushort4*)(xraw + e) = a;
    *(ushort4*)(cur + (size_t)row * CURW + col) = c;
    return;
  }
  int j = i - TX;
  const int PP = 130;
  if (j < BATCH * PP) {
    int row = j / PP, p = j - row * PP;
    int col = p < 58 ? 774 + p : (p < 98 ? 856 + (p - 58) : 992 + (p - 98));
    cur[(size_t)row * CURW + col] = 0;
  }
}

// ---------- padded-col -> real-col map ----------
__device__ __forceinline__ int pad2real(int kp) {
  if (kp < 774)  return kp;
  if (kp < 832)  return -1;
  if (kp < 856)  return 774 + (kp - 832);
  if (kp < 896)  return -1;
  if (kp < 992)  return 798 + (kp - 896);
  if (kp < 1024) return -1;
  if (kp < 1408) return 894 + (kp - 1024);
  return 1278 + (kp - 1408);
}

template<int KPAD, int KREAL, int NREAL>
__device__ __forceinline__ void convW(int rel, const float* __restrict__ W,
                                      unsigned short* __restrict__ Wp) {
  int n = rel / KPAD, kp = rel - n * KPAD;
  int kr = pad2real(kp);
  float v = 0.f;
  if (n < NREAL && kr >= 0) v = W[(size_t)n * KREAL + kr];
  Wp[rel] = f2bf(v);
}

// ---------- all weight conversions + inverse permutation in one launch ----------
__global__ void k_convert_w_all(const float* __restrict__ W0, const float* __restrict__ W1,
                                const float* __restrict__ W2, const float* __restrict__ W3,
                                const float* __restrict__ W4, const float* __restrict__ W5,
                                const int* __restrict__ labels, int* __restrict__ inv,
                                unsigned short* __restrict__ wp) {
  int i = blockIdx.x * 256 + threadIdx.x;
  if (i < NUM_LABELS) inv[labels[i]] = i;
  if (i >= 20963328) return;
  if (i < 319488) {
    if (i < 98304)       convW<768, 768, 6>  (i,          W0, wp);
    else if (i < 204800) convW<832, 774, 24> (i - 98304,  W1, wp + 98304);
    else                 convW<896, 798, 96> (i - 204800, W2, wp + 204800);
  } else {
    if (i < 712704)       convW<1024, 894, 384>  (i - 319488,  W3, wp + 319488);
    else if (i < 2875392) convW<1408, 1278, 1536>(i - 712704,  W4, wp + 712704);
    else                  convW<2944, 2814, 6144>(i - 2875392, W5, wp + 2875392);
  }
}

// ---------- fused levels 0-2 ----------
__global__ __launch_bounds__(256, 2) void k_fused_small(
    const unsigned short* __restrict__ xraw,
    const unsigned short* __restrict__ w0p,
    const unsigned short* __restrict__ w1p,
    const unsigned short* __restrict__ w2p,
    const float* __restrict__ b0, const float* __restrict__ b1,
    const float* __restrict__ b2,
    unsigned short* __restrict__ ybuf,
    unsigned short* __restrict__ cur) {
  __shared__ __align__(16) unsigned short As[32 * 1000];
  const int tid = threadIdx.x;
  const int l = tid & 63, w = tid >> 6;
  const int l15 = l & 15, q8 = (l >> 4) * 8;
  const int row0 = blockIdx.x * 32;
  const int mi = w >> 1;
  const int nj0 = w & 1;

  {
    const int r = tid >> 3, c8 = tid & 7;
    const unsigned short* src = xraw + (size_t)(row0 + r) * 768 + c8 * 96;
    unsigned short* dst = As + r * 1000 + c8 * 96;
#pragma unroll
    for (int i = 0; i < 12; ++i)
      *(bf16x8*)(dst + i * 8) = *(const bf16x8*)(src + i * 8);
    unsigned short* dz = As + r * 1000 + 768 + c8 * 28;
    ushort4 z = {0, 0, 0, 0};
#pragma unroll
    for (int i = 0; i < 7; ++i) *(ushort4*)(dz + i * 4) = z;
  }
  __syncthreads();

  auto level = [&](int K, int ntiles, int Nr, const unsigned short* W, int ldw,
                   const float* bias, int ycol, int ccol) {
    for (int n = nj0; n < ntiles; n += 2) {
      f32x4 acc = {0.f, 0.f, 0.f, 0.f};
      const unsigned short* wrow = W + (size_t)(n * 16 + l15) * ldw + q8;
      const unsigned short* arow = As + (mi * 16 + l15) * 1000 + q8;
#pragma unroll 2
      for (int k0 = 0; k0 < K; k0 += 32) {
        bf16x8 af = *(const bf16x8*)(arow + k0);
        bf16x8 bf = *(const bf16x8*)(wrow + k0);
        acc = __builtin_amdgcn_mfma_f32_16x16x32_bf16(af, bf, acc, 0, 0, 0);
      }
      int col = n * 16 + l15;
      if (col < Nr) {
        float bv = bias[col];
#pragma unroll
        for (int j = 0; j < 4; ++j) {
          int rl = mi * 16 + (l >> 4) * 4 + j;
          float y = acc[j] + bv;
          ybuf[(size_t)(row0 + rl) * YW + ycol + col] = f2bf(y);
          As[rl * 1000 + ccol + col] = f2bf(fmaxf(y, 0.f));
        }
      }
    }
    __syncthreads();
  };

  level(768, 1, 6,  w0p, 768, b0, 0,  768);

  {
    const int r = tid >> 3, c8 = tid & 7;
    unsigned short* p = As + r * 1000 + c8 * 96;
#pragma unroll
    for (int i = 0; i < 12; ++i) {
      bf16x8 v = *(bf16x8*)(p + i * 8);
#pragma unroll
      for (int j = 0; j < 8; ++j)
        if (((unsigned short)v[j]) & 0x8000u) v[j] = 0;
      *(bf16x8*)(p + i * 8) = v;
    }
  }
  __syncthreads();

  level(832, 2, 24, w1p, 832, b1, 6,  832);
  level(896, 6, 96, w2p, 896, b2, 30, 896);

  {
    const int r = tid >> 3, c8 = tid & 7;
    const unsigned short* srcl = As + r * 1000 + 768 + c8 * 28;
    unsigned short* dstg = cur + (size_t)(row0 + r) * CURW + 768 + c8 * 28;
#pragma unroll
    for (int i = 0; i < 7; ++i)
      *(ushort4*)(dstg + i * 4) = *(const ushort4*)(srcl + i * 4);
  }
}

// ---------- level-3 GEMM: 128x128 tile, 4 waves ----------
__global__ __launch_bounds__(256, 2) void k_gemm(
    const unsigned short* __restrict__ A, int lda,
    const unsigned short* __restrict__ B, int ldb,
    const float* __restrict__ bias,
    unsigned short* __restrict__ ybuf,
    unsigned short* __restrict__ curout,
    int K, int Nreal, int yoff, int curoff) {
  __shared__ unsigned short Asmem[128 * 64];
  __shared__ unsigned short Bsmem[128 * 64];
  const int tid = threadIdx.x;
  const int lane = tid & 63;
  const int wid = tid >> 6;
  const int wr = wid >> 1, wc = wid & 1;
  const int brow = blockIdx.x * 128;
  const int bcol = blockIdx.y * 128;

  f32x4 acc[4][4] = {};

  for (int k0 = 0; k0 < K; k0 += 64) {
#pragma unroll
    for (int p = 0; p < 4; ++p) {
      int ch = wid * 4 + p;
      int eo = ch * 512 + lane * 8;
      int r = eo >> 6;
      int col = eo & 63;
      gload_lds16(A + (size_t)(brow + r) * lda + k0 + col, Asmem + ch * 512);
      gload_lds16(B + (size_t)(bcol + r) * ldb + k0 + col, Bsmem + ch * 512);
    }
    __syncthreads();
#pragma unroll
    for (int kk = 0; kk < 2; ++kk) {
      bf16x8 af[4], bfr[4];
      int colk = kk * 32 + (lane >> 4) * 8;
#pragma unroll
      for (int m = 0; m < 4; ++m)
        af[m] = *(const bf16x8*)(Asmem + (wr * 64 + m * 16 + (lane & 15)) * 64 + colk);
#pragma unroll
      for (int n = 0; n < 4; ++n)
        bfr[n] = *(const bf16x8*)(Bsmem + (wc * 64 + n * 16 + (lane & 15)) * 64 + colk);
#pragma unroll
      for (int m = 0; m < 4; ++m)
#pragma unroll
        for (int n = 0; n < 4; ++n)
          acc[m][n] = __builtin_amdgcn_mfma_f32_16x16x32_bf16(af[m], bfr[n], acc[m][n], 0, 0, 0);
    }
    __syncthreads();
  }

#pragma unroll
  for (int n = 0; n < 4; ++n) {
    int col = bcol + wc * 64 + n * 16 + (lane & 15);
    if (col >= Nreal) continue;
    float bv = bias[col];
#pragma unroll
    for (int m = 0; m < 4; ++m) {
#pragma unroll
      for (int j = 0; j < 4; ++j) {
        int row = brow + wr * 64 + m * 16 + (lane >> 4) * 4 + j;
        float y = acc[m][n][j] + bv;
        ybuf[(size_t)row * YW + yoff + col] = f2bf(y);
        if (curout) curout[(size_t)row * CURW + curoff + col] = f2bf(fmaxf(y, 0.f));
      }
    }
  }
}

// ---------- big-level GEMM (levels 4-5): 256x256, 8 waves, 1-barrier/phase ----------
// Ledger: stages dB0x@P3, dA0x@P4, dB1x@P7, dA1x@P8 (4 gloads each).
// Publish: VMCNT(8) after MFMA at P4 (buf1) and P8 (buf0): 16 outstanding ->
// retires the 8 of the buffer read next phase; 4-phase prefetch depth.
// Hazard invariant: BAR at phase end follows a ladder that retires that
// phase's ds_reads, so a region last-read in phase p is restageable at p+1.
// Region last-reads: dB0x@P2(via P1-issued bF23, retired by P2 ladder),
// dA0x@P3, dB1x@P6, dA1x@P7 -> all stage placements have gap>=1. Correctness
// never depends on WAITK counts (compiler adds precise dep-waits).
__global__ __launch_bounds__(512, 2) void k_gemm256(
    const unsigned short* __restrict__ A, int lda,
    const unsigned short* __restrict__ B, int ldb,
    const float* __restrict__ bias,
    unsigned short* __restrict__ ybuf,
    unsigned short* __restrict__ curout,
    int K, int yoff, int curoff) {
  __shared__ __align__(16) unsigned short lds[65536];  // 128 KiB
  const int tid = threadIdx.x;
  const int l = tid & 63;
  const int w = tid >> 6;
  const int wr = w >> 2;
  const int wc = w & 3;
  const int l15 = l & 15;
  const int q8 = (l >> 4) * 8;
  const int sx = (l & 7) << 3;
  const int swz = ((l & 7) ^ (l >> 3)) * 8;

  const int bid = blockIdx.x;
  const int im = (bid & 7) * 4 + ((bid >> 3) & 3);
  const int in = bid >> 5;
  const int brow = im * 256, bcol = in * 256;

  const unsigned short* gAr0 = A + (size_t)(brow + w * 8 + (l >> 3)) * lda + swz;
  const unsigned short* gAr1 = gAr0 + (size_t)64 * lda;
  const unsigned short* gAr2 = gAr0 + (size_t)128 * lda;
  const unsigned short* gAr3 = gAr0 + (size_t)192 * lda;
  const unsigned short* gBr0 = B + (size_t)(bcol + w * 8 + (l >> 3)) * ldb + swz;
  const unsigned short* gBr1 = gBr0 + (size_t)64 * ldb;
  const unsigned short* gBr2 = gBr0 + (size_t)128 * ldb;
  const unsigned short* gBr3 = gBr0 + (size_t)192 * ldb;

  unsigned short* const dA00 = lds + w * 512;
  unsigned short* const dA01 = lds + 8192 + w * 512;
  unsigned short* const dA10 = lds + 16384 + w * 512;
  unsigned short* const dA11 = lds + 24576 + w * 512;
  unsigned short* const dB00 = lds + 32768 + w * 512;
  unsigned short* const dB01 = lds + 40960 + w * 512;
  unsigned short* const dB10 = lds + 49152 + w * 512;
  unsigned short* const dB11 = lds + 57344 + w * 512;

  const int cOff0 = (q8) ^ sx;
  const int cOff1 = (32 + q8) ^ sx;
  const int brB = (wc & 1) * 64;
  const unsigned short* const aB00 = lds + wr * 8192 + l15 * 64 + cOff0;
  const unsigned short* const aB01 = lds + wr * 8192 + l15 * 64 + cOff1;
  const unsigned short* const aB10 = lds + 16384 + wr * 8192 + l15 * 64 + cOff0;
  const unsigned short* const aB11 = lds + 16384 + wr * 8192 + l15 * 64 + cOff1;
  const unsigned short* const bB00 = lds + 32768 + (wc >> 1) * 8192 + (brB + l15) * 64 + cOff0;
  const unsigned short* const bB01 = lds + 32768 + (wc >> 1) * 8192 + (brB + l15) * 64 + cOff1;
  const unsigned short* const bB10 = lds + 49152 + (wc >> 1) * 8192 + (brB + l15) * 64 + cOff0;
  const unsigned short* const bB11 = lds + 49152 + (wc >> 1) * 8192 + (brB + l15) * 64 + cOff1;

  f32x4 acc[8][4] = {};
  bf16x8 aF[2][4], bF[2][4];

  auto stage2 = [&](const unsigned short* glo, const unsigned short* ghi,
                    unsigned short* dst, int koff) {
    gload_lds16(glo + koff, dst);
    gload_lds16(ghi + koff, dst + 4096);
  };
  auto ldB01f = [&](const unsigned short* lo, const unsigned short* hi) {
#pragma unroll
    for (int n = 0; n < 2; ++n) {
      bF[0][n] = *(const bf16x8*)(lo + n * 16 * 64);
      bF[1][n] = *(const bf16x8*)(hi + n * 16 * 64);
    }
  };
  auto ldB23f = [&](const unsigned short* lo, const unsigned short* hi) {
#pragma unroll
    for (int n = 2; n < 4; ++n) {
      bF[0][n] = *(const bf16x8*)(lo + n * 16 * 64);
      bF[1][n] = *(const bf16x8*)(hi + n * 16 * 64);
    }
  };
  auto ldAh = [&](const unsigned short* lo, const unsigned short* hi, int half) {
#pragma unroll
    for (int m = 0; m < 4; ++m) {
      aF[0][m] = *(const bf16x8*)(lo + (half * 64 + m * 16) * 64);
      aF[1][m] = *(const bf16x8*)(hi + (half * 64 + m * 16) * 64);
    }
  };
  auto MM4 = [&](int m, int mbase, int nbase) {
#pragma unroll
    for (int kk = 0; kk < 2; ++kk)
#pragma unroll
      for (int n = 0; n < 2; ++n)
        acc[mbase + m][nbase + n] = __builtin_amdgcn_mfma_f32_16x16x32_bf16(
            aF[kk][m], bF[kk][nbase + n], acc[mbase + m][nbase + n], 0, 0, 0);
  };
  auto MMAblk = [&](int mbase, int nbase) {
    __builtin_amdgcn_s_setprio(1);
#pragma unroll
    for (int kk = 0; kk < 2; ++kk)
#pragma unroll
      for (int m = 0; m < 4; ++m)
#pragma unroll
        for (int n = 0; n < 2; ++n)
          acc[mbase + m][nbase + n] = __builtin_amdgcn_mfma_f32_16x16x32_bf16(
              aF[kk][m], bF[kk][nbase + n], acc[mbase + m][nbase + n], 0, 0, 0);
    __builtin_amdgcn_s_setprio(0);
  };

  const int KT = K >> 6;
  const int NT2 = KT >> 1;

  // prologue: t0 -> buf0 (8 loads), t1 -> buf1 (8 loads); retire t0, keep t1
  stage2(gBr0, gBr1, dB00, 0);  stage2(gBr2, gBr3, dB01, 0);
  stage2(gAr0, gAr1, dA00, 0);  stage2(gAr2, gAr3, dA01, 0);
  stage2(gBr0, gBr1, dB10, 64); stage2(gBr2, gBr3, dB11, 64);
  stage2(gAr0, gAr1, dA10, 64); stage2(gAr2, gAr3, dA11, 64);
  VMCNT(8);
  BAR();

  for (int it = 0; it < NT2; ++it) {
    const bool more = (it + 1 < NT2);
    // P1: issue bF01(4), aFh0(8), bF23(4); ladder leaves bF23 in flight
    ldB01f(bB00, bB01);
    ldAh(aB00, aB01, 0);
    ldB23f(bB00, bB01);
    __builtin_amdgcn_s_setprio(1);
    WAITK(10); MM4(0, 0, 0);
    WAITK(8);  MM4(1, 0, 0);
    WAITK(6);  MM4(2, 0, 0);
    WAITK(4);  MM4(3, 0, 0);
    __builtin_amdgcn_s_setprio(0);
    BAR();
    // P2: drain bF23, 16 MFMA
    __builtin_amdgcn_s_setprio(1);
    WAITK(0);
    MMAblk(0, 2);
    BAR();
    // P3: stage dB0x@t2; read aFh1(8); ladder drains
    if (more) { stage2(gBr0, gBr1, dB00, 128); stage2(gBr2, gBr3, dB01, 128); }
    ldAh(aB00, aB01, 1);
    __builtin_amdgcn_s_setprio(1);
    WAITK(6); MM4(0, 4, 0);
    WAITK(4); MM4(1, 4, 0);
    WAITK(2); MM4(2, 4, 0);
    WAITK(0); MM4(3, 4, 0);
    __builtin_amdgcn_s_setprio(0);
    BAR();
    // P4: stage dA0x@t2; 16 MFMA; publish buf1 (retire t1)
    if (more) { stage2(gAr0, gAr1, dA00, 128); stage2(gAr2, gAr3, dA01, 128); }
    MMAblk(4, 2);
    if (more) { VMCNT(8); } else { VMCNT(0); }
    BAR();
    // P5: buf1
    ldB01f(bB10, bB11);
    ldAh(aB10, aB11, 0);
    ldB23f(bB10, bB11);
    __builtin_amdgcn_s_setprio(1);
    WAITK(10); MM4(0, 0, 0);
    WAITK(8);  MM4(1, 0, 0);
    WAITK(6);  MM4(2, 0, 0);
    WAITK(4);  MM4(3, 0, 0);
    __builtin_amdgcn_s_setprio(0);
    BAR();
    // P6
    __builtin_amdgcn_s_setprio(1);
    WAITK(0);
    MMAblk(0, 2);
    BAR();
    // P7: stage dB1x@t3
    if (more) { stage2(gBr0, gBr1, dB10, 192); stage2(gBr2, gBr3, dB11, 192); }
    ldAh(aB10, aB11, 1);
    __builtin_amdgcn_s_setprio(1);
    WAITK(6); MM4(0, 4, 0);
    WAITK(4); MM4(1, 4, 0);
    WAITK(2); MM4(2, 4, 0);
    WAITK(0); MM4(3, 4, 0);
    __builtin_amdgcn_s_setprio(0);
    BAR();
    // P8: stage dA1x@t3; 16 MFMA; publish buf0 (retire t2)
    if (more) { stage2(gAr0, gAr1, dA10, 192); stage2(gAr2, gAr3, dA11, 192); }
    MMAblk(4, 2);
    if (more) { VMCNT(8); }
    BAR();
    gAr0 += 128; gAr1 += 128; gAr2 += 128; gAr3 += 128;
    gBr0 += 128; gBr1 += 128; gBr2 += 128; gBr3 += 128;
  }

  // epilogue
  const int j4 = (l >> 4) * 4;
  float bv[4];
#pragma unroll
  for (int n = 0; n < 4; ++n) bv[n] = bias[bcol + wc * 64 + n * 16 + l15];
#pragma unroll
  for (int m = 0; m < 8; ++m) {
    int rowb = brow + wr * 128 + m * 16 + j4;
#pragma unroll
    for (int j = 0; j < 4; ++j) {
      size_t rbase = (size_t)(rowb + j);
#pragma unroll
      for (int n = 0; n < 4; ++n) {
        int col = bcol + wc * 64 + n * 16 + l15;
        float y = acc[m][n][j] + bv[n];
        ybuf[rbase * YW + yoff + col] = f2bf(y);
        if (curout) curout[rbase * CURW + curoff + col] = f2bf(fmaxf(y, 0.f));
      }
    }
  }
}

// ---------- final gather: float2 stores ----------
__global__ void k_gather(const unsigned short* __restrict__ ybuf,
                         const int* __restrict__ inv,
                         float* __restrict__ out) {
  const int half = NUM_LABELS / 2;   // 4095
  int i = blockIdx.x * 256 + threadIdx.x;
  if (i >= BATCH * half) return;
  int row = i / half;
  int c2 = (i - row * half) * 2;
  int2 iv = *(const int2*)(inv + c2);
  const unsigned short* yr = ybuf + (size_t)row * YW;
  float2 v;
  v.x = bf2f(yr[iv.x]);
  v.y = bf2f(yr[iv.y]);
  *(float2*)(out + (size_t)row * NUM_LABELS + c2) = v;
}

// ---------- launch ----------
extern "C" void kernel_launch(void* const* d_in, const int* in_sizes, int n_in,
                              void* d_out, int out_size, void* d_ws, size_t ws_size,
                              hipStream_t stream) {
  const float* x = (const float*)d_in[0];
  const float* W[6];
  const float* bias[6];
  for (int i = 0; i < 6; ++i) {
    W[i] = (const float*)d_in[1 + 2 * i];
    bias[i] = (const float*)d_in[2 + 2 * i];
  }
  const int* labels = (const int*)d_in[13];
  float* out = (float*)d_out;

  char* ws = (char*)d_ws;
  unsigned short* xraw = (unsigned short*)(ws);
  unsigned short* cur  = (unsigned short*)(ws + 12582912);
  unsigned short* wp   = (unsigned short*)(ws + 60817408);
  unsigned short* ybuf = (unsigned short*)(ws + 102744064);
  int* inv             = (int*)(ws + 236961792);

  static const int Kpad[6]   = {768, 832, 896, 1024, 1408, 2944};
  static const int Nreal[6]  = {6, 24, 96, 384, 1536, 6144};
  static const int Npad[6]   = {128, 128, 128, 384, 1536, 6144};
  static const size_t woff[6] = {0, 98304, 204800, 319488, 712704, 2875392};
  static const int yoff[6]   = {0, 6, 30, 126, 510, 2046};
  static const int curoff[6] = {768, 832, 896, 1024, 1408, 0};

  {
    int tot = BATCH * 768 / 4 + BATCH * 130;
    k_prep_x<<<(tot + 255) / 256, 256, 0, stream>>>(x, xraw, cur);
  }
  k_convert_w_all<<<(20963328 + 255) / 256, 256, 0, stream>>>(
      W[0], W[1], W[2], W[3], W[4], W[5], labels, inv, wp);

  // levels 0-2 fused
  k_fused_small<<<BATCH / 32, 256, 0, stream>>>(
      xraw, wp + woff[0], wp + woff[1], wp + woff[2],
      bias[0], bias[1], bias[2], ybuf, cur);

  // level 3: 128^2 kernel
  {
    dim3 grid(BATCH / 128, Npad[3] / 128);
    k_gemm<<<grid, 256, 0, stream>>>(cur, CURW, wp + woff[3], Kpad[3], bias[3], ybuf,
                                     cur, Kpad[3], Nreal[3], yoff[3], curoff[3]);
  }
  // levels 4-5: 256^2 kernel, 2D-XCD decode
  for (int i = 4; i < 6; ++i) {
    int nwg = (BATCH / 256) * (Npad[i] / 256);
    k_gemm256<<<nwg, 512, 0, stream>>>(cur, CURW, wp + woff[i], Kpad[i], bias[i], ybuf,
                                       (i < 5) ? cur : (unsigned short*)nullptr,
                                       Kpad[i], yoff[i], curoff[i]);
  }

  k_gather<<<(BATCH * (NUM_LABELS / 2) + 255) / 256, 256, 0, stream>>>(ybuf, inv, out);
}

// Round 9
// 525.978 us; speedup vs baseline: 1.1861x; 1.1861x over previous
//
#include <hip/hip_runtime.h>
#include <hip/hip_bf16.h>

#define BATCH 8192
#define NUM_LABELS 8190
#define CURW 2944   // padded cur width (K for level 5)
#define YW   8192   // ybuf row stride

typedef __attribute__((ext_vector_type(4))) float f32x4;
typedef __attribute__((ext_vector_type(8))) short bf16x8;

#define VMCNT(n) asm volatile("s_waitcnt vmcnt(" #n ")" ::: "memory")
#define BAR() do { asm volatile("" ::: "memory"); __builtin_amdgcn_s_barrier(); asm volatile("" ::: "memory"); } while (0)
#define WAITK(n) do { asm volatile("s_waitcnt lgkmcnt(" #n ")" ::: "memory"); __builtin_amdgcn_sched_barrier(0); } while (0)

// ---------- helpers ----------
__device__ __forceinline__ unsigned short f2bf(float f) {
  unsigned u = __builtin_bit_cast(unsigned, f);
  unsigned r = u + 0x7fffu + ((u >> 16) & 1u);   // RNE; inputs are finite
  return (unsigned short)(r >> 16);
}
__device__ __forceinline__ float bf2f(unsigned short b) {
  return __builtin_bit_cast(float, (unsigned)b << 16);
}
__device__ __forceinline__ void gload_lds16(const void* g, void* l) {
  __builtin_amdgcn_global_load_lds(
      (const __attribute__((address_space(1))) void*)g,
      (__attribute__((address_space(3))) void*)l,
      16, 0, 0);
}

// ---------- fused x-convert + pad-zeroing ----------
__global__ void k_prep_x(const float* __restrict__ x,
                         unsigned short* __restrict__ xraw,
                         unsigned short* __restrict__ cur) {
  const int TX = BATCH * 768 / 4;
  int i = blockIdx.x * 256 + threadIdx.x;
  if (i < TX) {
    float4 v = ((const float4*)x)[i];
    int e = i * 4;
    int row = e / 768;
    int col = e - row * 768;
    ushort4 a, c;
    a.x = f2bf(v.x); a.y = f2bf(v.y); a.z = f2bf(v.z); a.w = f2bf(v.w);
    c.x = f2bf(fmaxf(v.x, 0.f)); c.y = f2bf(fmaxf(v.y, 0.f));
    c.z = f2bf(fmaxf(v.z, 0.f)); c.w = f2bf(fmaxf(v.w, 0.f));
    *(ushort4*)(xraw + e) = a;
    *(ushort4*)(cur + (size_t)row * CURW + col) = c;
    return;
  }
  int j = i - TX;
  const int PP = 130;
  if (j < BATCH * PP) {
    int row = j / PP, p = j - row * PP;
    int col = p < 58 ? 774 + p : (p < 98 ? 856 + (p - 58) : 992 + (p - 98));
    cur[(size_t)row * CURW + col] = 0;
  }
}

// ---------- padded-col -> real-col map ----------
__device__ __forceinline__ int pad2real(int kp) {
  if (kp < 774)  return kp;
  if (kp < 832)  return -1;
  if (kp < 856)  return 774 + (kp - 832);
  if (kp < 896)  return -1;
  if (kp < 992)  return 798 + (kp - 896);
  if (kp < 1024) return -1;
  if (kp < 1408) return 894 + (kp - 1024);
  return 1278 + (kp - 1408);
}

template<int KPAD, int KREAL, int NREAL>
__device__ __forceinline__ void convW(int rel, const float* __restrict__ W,
                                      unsigned short* __restrict__ Wp) {
  int n = rel / KPAD, kp = rel - n * KPAD;
  int kr = pad2real(kp);
  float v = 0.f;
  if (n < NREAL && kr >= 0) v = W[(size_t)n * KREAL + kr];
  Wp[rel] = f2bf(v);
}

// ---------- all weight conversions + inverse permutation in one launch ----------
__global__ void k_convert_w_all(const float* __restrict__ W0, const float* __restrict__ W1,
                                const float* __restrict__ W2, const float* __restrict__ W3,
                                const float* __restrict__ W4, const float* __restrict__ W5,
                                const int* __restrict__ labels, int* __restrict__ inv,
                                unsigned short* __restrict__ wp) {
  int i = blockIdx.x * 256 + threadIdx.x;
  if (i < NUM_LABELS) inv[labels[i]] = i;
  if (i >= 20963328) return;
  if (i < 319488) {
    if (i < 98304)       convW<768, 768, 6>  (i,          W0, wp);
    else if (i < 204800) convW<832, 774, 24> (i - 98304,  W1, wp + 98304);
    else                 convW<896, 798, 96> (i - 204800, W2, wp + 204800);
  } else {
    if (i < 712704)       convW<1024, 894, 384>  (i - 319488,  W3, wp + 319488);
    else if (i < 2875392) convW<1408, 1278, 1536>(i - 712704,  W4, wp + 712704);
    else                  convW<2944, 2814, 6144>(i - 2875392, W5, wp + 2875392);
  }
}

// ---------- fused levels 0-2 ----------
__global__ __launch_bounds__(256, 2) void k_fused_small(
    const unsigned short* __restrict__ xraw,
    const unsigned short* __restrict__ w0p,
    const unsigned short* __restrict__ w1p,
    const unsigned short* __restrict__ w2p,
    const float* __restrict__ b0, const float* __restrict__ b1,
    const float* __restrict__ b2,
    unsigned short* __restrict__ ybuf,
    unsigned short* __restrict__ cur) {
  __shared__ __align__(16) unsigned short As[32 * 1000];
  const int tid = threadIdx.x;
  const int l = tid & 63, w = tid >> 6;
  const int l15 = l & 15, q8 = (l >> 4) * 8;
  const int row0 = blockIdx.x * 32;
  const int mi = w >> 1;
  const int nj0 = w & 1;

  {
    const int r = tid >> 3, c8 = tid & 7;
    const unsigned short* src = xraw + (size_t)(row0 + r) * 768 + c8 * 96;
    unsigned short* dst = As + r * 1000 + c8 * 96;
#pragma unroll
    for (int i = 0; i < 12; ++i)
      *(bf16x8*)(dst + i * 8) = *(const bf16x8*)(src + i * 8);
    unsigned short* dz = As + r * 1000 + 768 + c8 * 28;
    ushort4 z = {0, 0, 0, 0};
#pragma unroll
    for (int i = 0; i < 7; ++i) *(ushort4*)(dz + i * 4) = z;
  }
  __syncthreads();

  auto level = [&](int K, int ntiles, int Nr, const unsigned short* W, int ldw,
                   const float* bias, int ycol, int ccol) {
    for (int n = nj0; n < ntiles; n += 2) {
      f32x4 acc = {0.f, 0.f, 0.f, 0.f};
      const unsigned short* wrow = W + (size_t)(n * 16 + l15) * ldw + q8;
      const unsigned short* arow = As + (mi * 16 + l15) * 1000 + q8;
#pragma unroll 2
      for (int k0 = 0; k0 < K; k0 += 32) {
        bf16x8 af = *(const bf16x8*)(arow + k0);
        bf16x8 bf = *(const bf16x8*)(wrow + k0);
        acc = __builtin_amdgcn_mfma_f32_16x16x32_bf16(af, bf, acc, 0, 0, 0);
      }
      int col = n * 16 + l15;
      if (col < Nr) {
        float bv = bias[col];
#pragma unroll
        for (int j = 0; j < 4; ++j) {
          int rl = mi * 16 + (l >> 4) * 4 + j;
          float y = acc[j] + bv;
          ybuf[(size_t)(row0 + rl) * YW + ycol + col] = f2bf(y);
          As[rl * 1000 + ccol + col] = f2bf(fmaxf(y, 0.f));
        }
      }
    }
    __syncthreads();
  };

  level(768, 1, 6,  w0p, 768, b0, 0,  768);

  {
    const int r = tid >> 3, c8 = tid & 7;
    unsigned short* p = As + r * 1000 + c8 * 96;
#pragma unroll
    for (int i = 0; i < 12; ++i) {
      bf16x8 v = *(bf16x8*)(p + i * 8);
#pragma unroll
      for (int j = 0; j < 8; ++j)
        if (((unsigned short)v[j]) & 0x8000u) v[j] = 0;
      *(bf16x8*)(p + i * 8) = v;
    }
  }
  __syncthreads();

  level(832, 2, 24, w1p, 832, b1, 6,  832);
  level(896, 6, 96, w2p, 896, b2, 30, 896);

  {
    const int r = tid >> 3, c8 = tid & 7;
    const unsigned short* srcl = As + r * 1000 + 768 + c8 * 28;
    unsigned short* dstg = cur + (size_t)(row0 + r) * CURW + 768 + c8 * 28;
#pragma unroll
    for (int i = 0; i < 7; ++i)
      *(ushort4*)(dstg + i * 4) = *(const ushort4*)(srcl + i * 4);
  }
}

// ---------- level-3 GEMM: 128x128 tile, 4 waves ----------
__global__ __launch_bounds__(256, 2) void k_gemm(
    const unsigned short* __restrict__ A, int lda,
    const unsigned short* __restrict__ B, int ldb,
    const float* __restrict__ bias,
    unsigned short* __restrict__ ybuf,
    unsigned short* __restrict__ curout,
    int K, int Nreal, int yoff, int curoff) {
  __shared__ unsigned short Asmem[128 * 64];
  __shared__ unsigned short Bsmem[128 * 64];
  const int tid = threadIdx.x;
  const int lane = tid & 63;
  const int wid = tid >> 6;
  const int wr = wid >> 1, wc = wid & 1;
  const int brow = blockIdx.x * 128;
  const int bcol = blockIdx.y * 128;

  f32x4 acc[4][4] = {};

  for (int k0 = 0; k0 < K; k0 += 64) {
#pragma unroll
    for (int p = 0; p < 4; ++p) {
      int ch = wid * 4 + p;
      int eo = ch * 512 + lane * 8;
      int r = eo >> 6;
      int col = eo & 63;
      gload_lds16(A + (size_t)(brow + r) * lda + k0 + col, Asmem + ch * 512);
      gload_lds16(B + (size_t)(bcol + r) * ldb + k0 + col, Bsmem + ch * 512);
    }
    __syncthreads();
#pragma unroll
    for (int kk = 0; kk < 2; ++kk) {
      bf16x8 af[4], bfr[4];
      int colk = kk * 32 + (lane >> 4) * 8;
#pragma unroll
      for (int m = 0; m < 4; ++m)
        af[m] = *(const bf16x8*)(Asmem + (wr * 64 + m * 16 + (lane & 15)) * 64 + colk);
#pragma unroll
      for (int n = 0; n < 4; ++n)
        bfr[n] = *(const bf16x8*)(Bsmem + (wc * 64 + n * 16 + (lane & 15)) * 64 + colk);
#pragma unroll
      for (int m = 0; m < 4; ++m)
#pragma unroll
        for (int n = 0; n < 4; ++n)
          acc[m][n] = __builtin_amdgcn_mfma_f32_16x16x32_bf16(af[m], bfr[n], acc[m][n], 0, 0, 0);
    }
    __syncthreads();
  }

#pragma unroll
  for (int n = 0; n < 4; ++n) {
    int col = bcol + wc * 64 + n * 16 + (lane & 15);
    if (col >= Nreal) continue;
    float bv = bias[col];
#pragma unroll
    for (int m = 0; m < 4; ++m) {
#pragma unroll
      for (int j = 0; j < 4; ++j) {
        int row = brow + wr * 64 + m * 16 + (lane >> 4) * 4 + j;
        float y = acc[m][n][j] + bv;
        ybuf[(size_t)row * YW + yoff + col] = f2bf(y);
        if (curout) curout[(size_t)row * CURW + curoff + col] = f2bf(fmaxf(y, 0.f));
      }
    }
  }
}

// ---------- big-level GEMM (levels 4-5): 256x256, 8 waves ----------
// R7 measured-best variant: per phase, ds_reads issue up front, then a
// counted-lgkm MFMA ladder; 2 barriers/phase; deep vmcnt(6) staging ledger.
__global__ __launch_bounds__(512, 2) void k_gemm256(
    const unsigned short* __restrict__ A, int lda,
    const unsigned short* __restrict__ B, int ldb,
    const float* __restrict__ bias,
    unsigned short* __restrict__ ybuf,
    unsigned short* __restrict__ curout,
    int K, int yoff, int curoff) {
  __shared__ __align__(16) unsigned short lds[65536];  // 128 KiB
  const int tid = threadIdx.x;
  const int l = tid & 63;
  const int w = tid >> 6;
  const int wr = w >> 2;
  const int wc = w & 3;
  const int l15 = l & 15;
  const int q8 = (l >> 4) * 8;
  const int sx = (l & 7) << 3;
  const int swz = ((l & 7) ^ (l >> 3)) * 8;

  const int bid = blockIdx.x;
  const int im = (bid & 7) * 4 + ((bid >> 3) & 3);
  const int in = bid >> 5;
  const int brow = im * 256, bcol = in * 256;

  const unsigned short* gAr0 = A + (size_t)(brow + w * 8 + (l >> 3)) * lda + swz;
  const unsigned short* gAr1 = gAr0 + (size_t)64 * lda;
  const unsigned short* gAr2 = gAr0 + (size_t)128 * lda;
  const unsigned short* gAr3 = gAr0 + (size_t)192 * lda;
  const unsigned short* gBr0 = B + (size_t)(bcol + w * 8 + (l >> 3)) * ldb + swz;
  const unsigned short* gBr1 = gBr0 + (size_t)64 * ldb;
  const unsigned short* gBr2 = gBr0 + (size_t)128 * ldb;
  const unsigned short* gBr3 = gBr0 + (size_t)192 * ldb;

  unsigned short* const dA00 = lds + w * 512;
  unsigned short* const dA01 = lds + 8192 + w * 512;
  unsigned short* const dA10 = lds + 16384 + w * 512;
  unsigned short* const dA11 = lds + 24576 + w * 512;
  unsigned short* const dB00 = lds + 32768 + w * 512;
  unsigned short* const dB01 = lds + 40960 + w * 512;
  unsigned short* const dB10 = lds + 49152 + w * 512;
  unsigned short* const dB11 = lds + 57344 + w * 512;

  const int cOff0 = (q8) ^ sx;
  const int cOff1 = (32 + q8) ^ sx;
  const int brB = (wc & 1) * 64;
  const unsigned short* const aB00 = lds + wr * 8192 + l15 * 64 + cOff0;
  const unsigned short* const aB01 = lds + wr * 8192 + l15 * 64 + cOff1;
  const unsigned short* const aB10 = lds + 16384 + wr * 8192 + l15 * 64 + cOff0;
  const unsigned short* const aB11 = lds + 16384 + wr * 8192 + l15 * 64 + cOff1;
  const unsigned short* const bB00 = lds + 32768 + (wc >> 1) * 8192 + (brB + l15) * 64 + cOff0;
  const unsigned short* const bB01 = lds + 32768 + (wc >> 1) * 8192 + (brB + l15) * 64 + cOff1;
  const unsigned short* const bB10 = lds + 49152 + (wc >> 1) * 8192 + (brB + l15) * 64 + cOff0;
  const unsigned short* const bB11 = lds + 49152 + (wc >> 1) * 8192 + (brB + l15) * 64 + cOff1;

  f32x4 acc[8][4] = {};
  bf16x8 aF[2][4], bF[2][4];

  auto stage2 = [&](const unsigned short* glo, const unsigned short* ghi,
                    unsigned short* dst, int koff) {
    gload_lds16(glo + koff, dst);
    gload_lds16(ghi + koff, dst + 4096);
  };
  auto ldAh = [&](const unsigned short* lo, const unsigned short* hi, int half) {
#pragma unroll
    for (int m = 0; m < 4; ++m) {
      aF[0][m] = *(const bf16x8*)(lo + (half * 64 + m * 16) * 64);
      aF[1][m] = *(const bf16x8*)(hi + (half * 64 + m * 16) * 64);
    }
  };
  auto ldB01f = [&](const unsigned short* lo, const unsigned short* hi) {
#pragma unroll
    for (int n = 0; n < 2; ++n) {
      bF[0][n] = *(const bf16x8*)(lo + n * 16 * 64);
      bF[1][n] = *(const bf16x8*)(hi + n * 16 * 64);
    }
  };
  auto ldB23f = [&](const unsigned short* lo, const unsigned short* hi) {
#pragma unroll
    for (int n = 2; n < 4; ++n) {
      bF[0][n] = *(const bf16x8*)(lo + n * 16 * 64);
      bF[1][n] = *(const bf16x8*)(hi + n * 16 * 64);
    }
  };
  auto MM4 = [&](int m, int mbase, int nbase) {   // 4 MFMA for one m
#pragma unroll
    for (int kk = 0; kk < 2; ++kk)
#pragma unroll
      for (int n = 0; n < 2; ++n)
        acc[mbase + m][nbase + n] = __builtin_amdgcn_mfma_f32_16x16x32_bf16(
            aF[kk][m], bF[kk][nbase + n], acc[mbase + m][nbase + n], 0, 0, 0);
  };
  auto MMAblk = [&](int mbase, int nbase) {       // 16 MFMA
    __builtin_amdgcn_s_setprio(1);
#pragma unroll
    for (int kk = 0; kk < 2; ++kk)
#pragma unroll
      for (int m = 0; m < 4; ++m)
#pragma unroll
        for (int n = 0; n < 2; ++n)
          acc[mbase + m][nbase + n] = __builtin_amdgcn_mfma_f32_16x16x32_bf16(
              aF[kk][m], bF[kk][nbase + n], acc[mbase + m][nbase + n], 0, 0, 0);
    __builtin_amdgcn_s_setprio(0);
  };

#define LADDER(mb, nb, w0, w1, w2, w3) do { \
    __builtin_amdgcn_s_setprio(1); \
    WAITK(w0); MM4(0, mb, nb); \
    WAITK(w1); MM4(1, mb, nb); \
    WAITK(w2); MM4(2, mb, nb); \
    WAITK(w3); MM4(3, mb, nb); \
    __builtin_amdgcn_s_setprio(0); \
  } while (0)

  const int KT = K >> 6;
  const int NT2 = KT >> 1;

  // prologue: t0 complete (8 loads) + t1 partial B0,B1,A-h0 (6 loads)
  stage2(gBr0, gBr1, dB00, 0);
  stage2(gBr2, gBr3, dB01, 0);
  stage2(gAr0, gAr1, dA00, 0);
  stage2(gAr2, gAr3, dA01, 0);
  stage2(gBr0, gBr1, dB10, 64);
  stage2(gBr2, gBr3, dB11, 64);
  stage2(gAr0, gAr1, dA10, 64);
  VMCNT(6);          // t0 published
  BAR();
  ldB01f(bB00, bB01);   // prime B01@buf0 (4 reads in flight)

  for (int it = 0; it < NT2; ++it) {
    const bool more = (it + 1 < NT2);
    // P1: Ah0@buf0 x B01   (entry: 4 B01 reads outstanding)
    stage2(gAr2, gAr3, dA11, 64);
    ldAh(aB00, aB01, 0);        // 8 reads
    ldB23f(bB00, bB01);         // 4 reads (used P2)
    LADDER(0, 0, 10, 8, 6, 4);
    BAR();
    // P2: Ah0 x B23 (no new reads)
    MMAblk(0, 2);
    BAR();
    // P3: Ah1@buf0 x B01
    if (more) stage2(gBr0, gBr1, dB00, 128);
    ldAh(aB00, aB01, 1);        // 8 reads
    LADDER(4, 0, 6, 4, 2, 0);
    BAR();
    // P4: Ah1 x B23 ; publish buf1@t1; preload B01@buf1
    if (more) { stage2(gBr2, gBr3, dB01, 128); stage2(gAr0, gAr1, dA00, 128); VMCNT(6); }
    else      { VMCNT(0); }
    BAR();
    ldB01f(bB10, bB11);         // 4 reads (used P5/P7)
    MMAblk(4, 2);
    BAR();
    // P5: Ah0@buf1 x B01'
    if (more) stage2(gAr2, gAr3, dA01, 128);
    ldAh(aB10, aB11, 0);
    ldB23f(bB10, bB11);
    LADDER(0, 0, 10, 8, 6, 4);
    BAR();
    // P6: Ah0 x B23'
    MMAblk(0, 2);
    BAR();
    // P7: Ah1@buf1 x B01'
    if (more) stage2(gBr0, gBr1, dB10, 192);
    ldAh(aB10, aB11, 1);
    LADDER(4, 0, 6, 4, 2, 0);
    BAR();
    // P8: Ah1 x B23' ; publish buf0@t2; preload next B01@buf0
    if (more) { stage2(gBr2, gBr3, dB11, 192); stage2(gAr0, gAr1, dA10, 192); VMCNT(6); }
    BAR();
    if (more) ldB01f(bB00, bB01);
    MMAblk(4, 2);
    BAR();
    gAr0 += 128; gAr1 += 128; gAr2 += 128; gAr3 += 128;
    gBr0 += 128; gBr1 += 128; gBr2 += 128; gBr3 += 128;
  }
#undef LADDER

  // epilogue
  const int j4 = (l >> 4) * 4;
  float bv[4];
#pragma unroll
  for (int n = 0; n < 4; ++n) bv[n] = bias[bcol + wc * 64 + n * 16 + l15];
#pragma unroll
  for (int m = 0; m < 8; ++m) {
    int rowb = brow + wr * 128 + m * 16 + j4;
#pragma unroll
    for (int j = 0; j < 4; ++j) {
      size_t rbase = (size_t)(rowb + j);
#pragma unroll
      for (int n = 0; n < 4; ++n) {
        int col = bcol + wc * 64 + n * 16 + l15;
        float y = acc[m][n][j] + bv[n];
        ybuf[rbase * YW + yoff + col] = f2bf(y);
        if (curout) curout[rbase * CURW + curoff + col] = f2bf(fmaxf(y, 0.f));
      }
    }
  }
}

// ---------- final gather: one row per block; ybuf row is L1-resident ----------
__global__ __launch_bounds__(256) void k_gather(
    const unsigned short* __restrict__ ybuf,
    const int* __restrict__ inv,
    float* __restrict__ out) {
  const int row = blockIdx.x;
  const unsigned short* yr = ybuf + (size_t)row * YW;
  float* orow = out + (size_t)row * NUM_LABELS;
  const int t = threadIdx.x;
#pragma unroll
  for (int it = 0; it < 16; ++it) {
    int idx = it * 256 + t;               // float2 slot in [0, 4095)
    if (idx < NUM_LABELS / 2) {
      int c2 = idx * 2;
      int2 iv = *(const int2*)(inv + c2);
      float2 v;
      v.x = bf2f(yr[iv.x]);
      v.y = bf2f(yr[iv.y]);
      *(float2*)(orow + c2) = v;
    }
  }
}

// ---------- launch ----------
extern "C" void kernel_launch(void* const* d_in, const int* in_sizes, int n_in,
                              void* d_out, int out_size, void* d_ws, size_t ws_size,
                              hipStream_t stream) {
  const float* x = (const float*)d_in[0];
  const float* W[6];
  const float* bias[6];
  for (int i = 0; i < 6; ++i) {
    W[i] = (const float*)d_in[1 + 2 * i];
    bias[i] = (const float*)d_in[2 + 2 * i];
  }
  const int* labels = (const int*)d_in[13];
  float* out = (float*)d_out;

  char* ws = (char*)d_ws;
  unsigned short* xraw = (unsigned short*)(ws);
  unsigned short* cur  = (unsigned short*)(ws + 12582912);
  unsigned short* wp   = (unsigned short*)(ws + 60817408);
  unsigned short* ybuf = (unsigned short*)(ws + 102744064);
  int* inv             = (int*)(ws + 236961792);

  static const int Kpad[6]   = {768, 832, 896, 1024, 1408, 2944};
  static const int Nreal[6]  = {6, 24, 96, 384, 1536, 6144};
  static const int Npad[6]   = {128, 128, 128, 384, 1536, 6144};
  static const size_t woff[6] = {0, 98304, 204800, 319488, 712704, 2875392};
  static const int yoff[6]   = {0, 6, 30, 126, 510, 2046};
  static const int curoff[6] = {768, 832, 896, 1024, 1408, 0};

  {
    int tot = BATCH * 768 / 4 + BATCH * 130;
    k_prep_x<<<(tot + 255) / 256, 256, 0, stream>>>(x, xraw, cur);
  }
  k_convert_w_all<<<(20963328 + 255) / 256, 256, 0, stream>>>(
      W[0], W[1], W[2], W[3], W[4], W[5], labels, inv, wp);

  // levels 0-2 fused
  k_fused_small<<<BATCH / 32, 256, 0, stream>>>(
      xraw, wp + woff[0], wp + woff[1], wp + woff[2],
      bias[0], bias[1], bias[2], ybuf, cur);

  // level 3: 128^2 kernel
  {
    dim3 grid(BATCH / 128, Npad[3] / 128);
    k_gemm<<<grid, 256, 0, stream>>>(cur, CURW, wp + woff[3], Kpad[3], bias[3], ybuf,
                                     cur, Kpad[3], Nreal[3], yoff[3], curoff[3]);
  }
  // levels 4-5: 256^2 kernel, 2D-XCD decode
  for (int i = 4; i < 6; ++i) {
    int nwg = (BATCH / 256) * (Npad[i] / 256);
    k_gemm256<<<nwg, 512, 0, stream>>>(cur, CURW, wp + woff[i], Kpad[i], bias[i], ybuf,
                                       (i < 5) ? cur : (unsigned short*)nullptr,
                                       Kpad[i], yoff[i], curoff[i]);
  }

  k_gather<<<BATCH, 256, 0, stream>>>(ybuf, inv, out);
}